// Round 24
// baseline (38.577 us; speedup 1.0000x reference)
//
#include <hip/hip_runtime.h>

#define B 16384
#define C 4
#define M 512
#define D 512
#define NSEG 64   // B/256 candidate segments
#define QSCALE 16777216.0f   // 2^24 fixed-point scale for deterministic atomics
#define BCAP_G 2048          // global boundary list capacity
#define BCAP_S 1024          // LDS copy capacity in kB (expected nb ~ 44)

// normalize -0.0 -> +0.0 so positive-float bit ordering is valid
__device__ inline unsigned posbits(float e)
{
    unsigned b = __float_as_uint(e);
    return (b == 0x80000000u) ? 0u : b;
}
// monotone (non-strict) 8-bit bin of the entropy; ent in [0, ln4]
__device__ inline int binOfBits(unsigned bits)
{
    float e = __uint_as_float(bits);
    float s = fminf(fmaxf(e * 12000000.0f, 0.0f), 16777215.0f);
    return (int)((unsigned)s >> 16);
}

// ---------------- K0: zero global hist + bnum (graph-safe, every call) -----
__global__ void k0_zero(int* __restrict__ hist, int* __restrict__ bnumG)
{
    int t = threadIdx.x;
    #pragma unroll
    for (int i = 0; i < 4; i++) hist[i * 256 + t] = 0;
    if (t == 0) *bnumG = 0;
}

// ---------------- K1: stats + candList + global histogram ------------------
__global__ __launch_bounds__(256) void k1_stats(
    const float* __restrict__ logits,
    const float* __restrict__ ent_memo,
    float* __restrict__ out,
    int* __restrict__ blockCnt,
    uint2* __restrict__ candList,
    unsigned long long* __restrict__ SQ,
    int* __restrict__ hist)
{
    __shared__ int wscan[4];
    __shared__ int lh[1024];            // [lab*256+bin]
    const int tid = threadIdx.x, blk = blockIdx.x;
    const int gid = blk * 256 + tid;
    const int lane = tid & 63, wv = tid >> 6;

    for (int i = tid; i < 1024; i += 256) lh[i] = 0;

    float4 l = *reinterpret_cast<const float4*>(logits + (size_t)gid * 4);
    float m = l.x; int idx = 0;
    if (l.y > m) { m = l.y; idx = 1; }
    if (l.z > m) { m = l.z; idx = 2; }
    if (l.w > m) { m = l.w; idx = 3; }
    float e0 = expf(l.x - m), e1 = expf(l.y - m), e2 = expf(l.z - m), e3 = expf(l.w - m);
    float s = e0 + e1 + e2 + e3;
    float inv = 1.0f / s;
    float p0 = e0 * inv, p1 = e1 * inv, p2 = e2 * inv, p3 = e3 * inv;
    float lse = logf(s);
    float ent = -(p0 * (l.x - m - lse) + p1 * (l.y - m - lse)
                + p2 * (l.z - m - lse) + p3 * (l.w - m - lse));
    float4 pr = { p0, p1, p2, p3 };
    *reinterpret_cast<float4*>(out + (size_t)B * 4 + (size_t)gid * 4) = pr;
    out[(size_t)B * 8 + gid] = ent;

    if (gid < C * M) SQ[gid] = 0ULL;

    float amax = ent_memo[(idx << 9) + M - 1];
    bool flag = ent < amax;
    unsigned bits = posbits(ent);
    __syncthreads();                     // lh zeroed

    if (flag) atomicAdd(&lh[(idx << 8) | binOfBits(bits)], 1);
    if (blk < 8) {                       // memo rows ride on blocks 0..7
        unsigned mb = posbits(ent_memo[gid]);
        atomicAdd(&lh[((gid >> 9) << 8) | binOfBits(mb)], 1);
    }

    // block-level compaction (order = b ascending within segment)
    unsigned long long mask = __ballot(flag);
    int prefix = __popcll(mask & ((1ull << lane) - 1ull));
    if (lane == 0) wscan[wv] = __popcll(mask);
    __syncthreads();                     // wscan ready + lh adds done
    int base = 0;
    for (int w = 0; w < wv; w++) base += wscan[w];
    if (flag)
        candList[blk * 256 + base + prefix] =
            make_uint2(bits, ((unsigned)idx << 14) | (unsigned)gid);
    if (tid == 0)
        blockCnt[blk] = wscan[0] + wscan[1] + wscan[2] + wscan[3];

    // merge private hist -> global (distinct addresses, low contention)
    for (int i = tid; i < 1024; i += 256) {
        int h = lh[i];
        if (h) atomicAdd(&hist[i], h);
    }
}

// ---------------- KT: scan + boundary extraction (72 blocks, no reduce) ----
__global__ __launch_bounds__(256) void kT_extract(
    const int* __restrict__ blockCnt,
    const uint2* __restrict__ candList,
    const float* __restrict__ ent_memo,
    const int* __restrict__ hist,
    int* __restrict__ mremG,
    int* __restrict__ bnumG,
    unsigned long long* __restrict__ bkeysG,
    int* __restrict__ blabsG)
{
    __shared__ int hist_s[1024];
    __shared__ int betaS[4], mremS[4];
    const int x = blockIdx.x, tid = threadIdx.x;
    const int lane = tid & 63, sg = tid >> 6;

    for (int i = tid; i < 1024; i += 256) hist_s[i] = hist[i];
    __syncthreads();

    // per-wave scan (wave w = label w), barrier-free within wave
    if (sg < 4) {
        int b0 = hist_s[(sg << 8) | (lane * 4 + 0)];
        int b1 = hist_s[(sg << 8) | (lane * 4 + 1)];
        int b2 = hist_s[(sg << 8) | (lane * 4 + 2)];
        int b3 = hist_s[(sg << 8) | (lane * 4 + 3)];
        int loc = b0 + b1 + b2 + b3;
        int scan = loc;
        #pragma unroll
        for (int off = 1; off < 64; off <<= 1) {
            int n = __shfl_up(scan, off, 64);
            if (lane >= off) scan += n;
        }
        int excl = scan - loc;
        int c0 = excl + b0, c1 = c0 + b1, c2 = c1 + b2, c3 = c2 + b3;
        if (excl < M && c3 >= M) {          // exactly one lane per label
            int beta, mrem;
            if (c0 >= M)      { beta = lane * 4 + 0; mrem = M - excl; }
            else if (c1 >= M) { beta = lane * 4 + 1; mrem = M - c0; }
            else if (c2 >= M) { beta = lane * 4 + 2; mrem = M - c1; }
            else              { beta = lane * 4 + 3; mrem = M - c2; }
            betaS[sg] = beta; mremS[sg] = mrem;
        }
    }
    __syncthreads();
    if (x == 0 && tid < 4) mremG[tid] = mremS[tid];

    if (x < NSEG) {
        uint2 v = candList[x * 256 + tid];
        int lab = (int)((v.y >> 14) & 3);
        if (tid < blockCnt[x] && binOfBits(v.x) == betaS[lab]) {
            int id = atomicAdd(bnumG, 1);
            if (id < BCAP_G) {
                bkeysG[id] = ((unsigned long long)v.x << 15)
                           | (unsigned)(512 + (v.y & 0x3FFF));
                blabsG[id] = lab;
            }
        }
    } else {
        int i = (x - NSEG) * 256 + tid;     // [0, C*M)
        unsigned bits = posbits(ent_memo[i]);
        int lab = i >> 9;
        if (binOfBits(bits) == betaS[lab]) {
            int id = atomicAdd(bnumG, 1);
            if (id < BCAP_G) {
                bkeysG[id] = ((unsigned long long)bits << 15) | (unsigned)(i & (M - 1));
                blabsG[id] = lab;
            }
        }
    }
}

// ---------------- KB: light preamble + compacted gather -> SQ --------------
// blocks 0..511: batch, seg = x>>3, colchunk q = x&7.  512..575: memo groups.
__global__ __launch_bounds__(256) void kB_acc(
    const int* __restrict__ blockCnt,
    const uint2* __restrict__ candList,
    const float* __restrict__ ent_memo,
    const int* __restrict__ mremG,
    const int* __restrict__ bnumG,
    const unsigned long long* __restrict__ bkeysG,
    const int* __restrict__ blabsG,
    const float* __restrict__ text_memo,
    const float* __restrict__ text_embeds,
    unsigned long long* __restrict__ SQ)
{
    __shared__ unsigned long long bkeys[BCAP_S];  // 8 KB
    __shared__ int blabs[BCAP_S];                 // 4 KB
    __shared__ int mremS[4];
    __shared__ unsigned long long TkeyS[4];
    __shared__ int meta[256];
    __shared__ int wscan[4];
    __shared__ int kcS;
    __shared__ float red[4][4][64];               // 4 KB [sg][label][lane]

    const int x = blockIdx.x, tid = threadIdx.x;
    const int col0 = (x & 7) << 6;
    const int lane = tid & 63, sg = tid >> 6;

    // ---- light select preamble (identical & deterministic in every block) -
    int nb = *bnumG; if (nb > BCAP_S) nb = BCAP_S;
    if (tid < 4) { mremS[tid] = mremG[tid]; TkeyS[tid] = ~0ULL; }
    for (int i = tid; i < nb; i += 256) { bkeys[i] = bkeysG[i]; blabs[i] = blabsG[i]; }
    __syncthreads();
    for (int t = tid; t < nb; t += 256) {
        unsigned long long k = bkeys[t]; int l = blabs[t];
        int r = 0;
        for (int j = 0; j < nb; j++)
            if (blabs[j] == l && bkeys[j] < k) r++;
        if (r == mremS[l] - 1) TkeyS[l] = k;      // unique winner (keys unique)
    }
    __syncthreads();                              // TkeyS visible to all waves

    if (x < 512) {
        const int seg = x >> 3;
        const int cnt = blockCnt[seg];
        // ---- ballot-compact kept slots (slot-ascending, deterministic) ----
        {
            uint2 v = candList[(seg << 8) + tid];
            int lab = (int)((v.y >> 14) & 3);
            unsigned long long key = ((unsigned long long)v.x << 15)
                                   | (unsigned)(512 + (v.y & 0x3FFF));
            bool kept = (tid < cnt) && (key <= TkeyS[lab]);
            unsigned long long kmask = __ballot(kept);
            int prefix = __popcll(kmask & ((1ull << lane) - 1ull));
            if (lane == 0) wscan[sg] = __popcll(kmask);
            meta[tid] = 0;                        // zero-pad (kept bit clear)
            __syncthreads();
            int base = 0;
            for (int w = 0; w < sg; w++) base += wscan[w];
            if (kept)
                meta[base + prefix] = (int)((unsigned)lab | 4u | ((v.y & 0x3FFF) << 3));
            if (tid == 0) kcS = wscan[0] + wscan[1] + wscan[2] + wscan[3];
            __syncthreads();
        }
        const int kcp = (kcS + 31) & ~31;         // padded to 32 (pads add 0)
        float a0 = 0.f, a1 = 0.f, a2 = 0.f, a3 = 0.f;
        for (int i0 = 0; i0 < kcp; i0 += 32) {
            int mts[8]; float vvs[8];
            #pragma unroll
            for (int u = 0; u < 8; u++)
                mts[u] = meta[i0 + ((u << 2) | sg)];
            #pragma unroll
            for (int u = 0; u < 8; u++)
                vvs[u] = text_embeds[(size_t)(mts[u] >> 3) * D + col0 + lane];
            #pragma unroll
            for (int u = 0; u < 8; u++) {
                bool kept = (mts[u] & 4) != 0;
                int lb = mts[u] & 3;
                float vv = vvs[u];
                a0 += (kept && lb == 0) ? vv : 0.f;
                a1 += (kept && lb == 1) ? vv : 0.f;
                a2 += (kept && lb == 2) ? vv : 0.f;
                a3 += (kept && lb == 3) ? vv : 0.f;
            }
        }
        red[sg][0][lane] = a0; red[sg][1][lane] = a1;
        red[sg][2][lane] = a2; red[sg][3][lane] = a3;
        __syncthreads();
        {
            int lab = tid >> 6, ln = tid & 63;
            float t = ((red[0][lab][ln] + red[1][lab][ln])
                     + red[2][lab][ln]) + red[3][lab][ln];   // fixed order
            long long q = llrintf(t * QSCALE);
            atomicAdd(&SQ[(lab << 9) + col0 + ln], (unsigned long long)q);
        }
    } else {
        const int g = (x - 512) >> 3;               // rowgroup 0..7
        const int c = g >> 1;                       // label
        const int base = g << 8;                    // first global memo row
        {
            int i = base + tid;
            unsigned bits = posbits(ent_memo[i]);
            unsigned long long key = ((unsigned long long)bits << 15)
                                   | (unsigned)(i & (M - 1));
            meta[tid] = (key <= TkeyS[c]) ? 1 : 0;
        }
        __syncthreads();
        float a = 0.f;
        #pragma unroll
        for (int kb = 0; kb < 8; kb++) {
            float vvs[8];
            #pragma unroll
            for (int u = 0; u < 8; u++)
                vvs[u] = text_memo[(size_t)(base + ((((kb << 3) | u) << 2) | sg)) * D + col0 + lane];
            #pragma unroll
            for (int u = 0; u < 8; u++)
                a += meta[(((kb << 3) | u) << 2) | sg] ? vvs[u] : 0.f;
        }
        red[sg][0][lane] = a;
        __syncthreads();
        if (tid < 64) {
            float t = ((red[0][0][tid] + red[1][0][tid])
                     + red[2][0][tid]) + red[3][0][tid];     // fixed order
            long long q = llrintf(t * QSCALE);
            atomicAdd(&SQ[(c << 9) + col0 + tid], (unsigned long long)q);
        }
    }
}

// ---------------- KC: SQ->VGPR S + GEMV + combines + softmaxes -------------
__global__ __launch_bounds__(256) void kC_cosin(
    const unsigned long long* __restrict__ SQ,
    const float* __restrict__ text_embeds,
    float* __restrict__ out)
{
    const int tid = threadIdx.x;
    const int wave = tid >> 6, lane = tid & 63;
    const float sc = 1.0f / QSCALE;
    float s0[8], s1[8], s2[8], s3[8];
    #pragma unroll
    for (int j = 0; j < 8; j++) {
        s0[j] = (float)(long long)SQ[0 * 512 + lane * 8 + j] * sc;
        s1[j] = (float)(long long)SQ[1 * 512 + lane * 8 + j] * sc;
        s2[j] = (float)(long long)SQ[2 * 512 + lane * 8 + j] * sc;
        s3[j] = (float)(long long)SQ[3 * 512 + lane * 8 + j] * sc;
    }
    for (int r4 = 0; r4 < 4; r4++) {
        int b = blockIdx.x * 16 + wave * 4 + r4;
        const float4* te4 = reinterpret_cast<const float4*>(text_embeds + (size_t)b * D);
        float4 t0 = te4[lane * 2], t1 = te4[lane * 2 + 1];
        float te[8] = { t0.x, t0.y, t0.z, t0.w, t1.x, t1.y, t1.z, t1.w };
        float c0 = 0.f, c1 = 0.f, c2 = 0.f, c3 = 0.f;
        #pragma unroll
        for (int j = 0; j < 8; j++) {
            c0 += te[j] * s0[j];
            c1 += te[j] * s1[j];
            c2 += te[j] * s2[j];
            c3 += te[j] * s3[j];
        }
        for (int off = 32; off; off >>= 1) {
            c0 += __shfl_down(c0, off, 64);
            c1 += __shfl_down(c1, off, 64);
            c2 += __shfl_down(c2, off, 64);
            c3 += __shfl_down(c3, off, 64);
        }
        if (lane == 0) {
            float t0c = c0 + c2, t1c = c1 + c3;   // text_combine
            float v0c = c0 + c1, v1c = c2 + c3;   // vision_combine
            float tm = fmaxf(t0c, t1c);
            float te0 = expf(t0c - tm), te1 = expf(t1c - tm);
            float ts = te0 + te1;
            float mt0 = te0 / ts, mt1 = te1 / ts;
            float vm = fmaxf(v0c, v1c);
            float ve0 = expf(v0c - vm), ve1 = expf(v1c - vm);
            float vs = ve0 + ve1;
            float mv0 = ve0 / vs, mv1 = ve1 / vs;
            float4 o = { mt0 * mv0, mt1 * mv0, mt0 * mv1, mt1 * mv1 };
            *reinterpret_cast<float4*>(out + (size_t)b * 4) = o;
        }
    }
}

// ---------------------------------------------------------------------------
extern "C" void kernel_launch(void* const* d_in, const int* in_sizes, int n_in,
                              void* d_out, int out_size, void* d_ws, size_t ws_size,
                              hipStream_t stream)
{
    (void)in_sizes; (void)n_in; (void)out_size; (void)ws_size;
    const float* logits      = (const float*)d_in[0];
    const float* text_embeds = (const float*)d_in[1];
    const float* ent_memo    = (const float*)d_in[3];
    const float* text_memo   = (const float*)d_in[4];
    float* out = (float*)d_out;
    char* ws = (char*)d_ws;

    // workspace layout (bytes), 256-aligned
    int*   blockCnt = (int*)(ws + 0);                        // 256 B
    uint2* candList = (uint2*)(ws + 256);                    // 128 KB -> 131328
    unsigned long long* SQ = (unsigned long long*)(ws + 131328); // 16 KB -> 147712
    int*   hist     = (int*)(ws + 147712);                   // 4 KB   -> 151808
    int*   mremG    = (int*)(ws + 151808);                   // 64 B
    int*   bnumG    = (int*)(ws + 152064);                   // 64 B
    unsigned long long* bkeysG = (unsigned long long*)(ws + 152320); // 16 KB -> 168704
    int*   blabsG   = (int*)(ws + 168704);                   // 8 KB -> 176896

    k0_zero<<<1, 256, 0, stream>>>(hist, bnumG);
    k1_stats<<<NSEG, 256, 0, stream>>>(logits, ent_memo, out, blockCnt,
                                       candList, SQ, hist);
    kT_extract<<<NSEG + 8, 256, 0, stream>>>(blockCnt, candList, ent_memo,
                                             hist, mremG, bnumG,
                                             bkeysG, blabsG);
    kB_acc<<<576, 256, 0, stream>>>(blockCnt, candList, ent_memo,
                                    mremG, bnumG, bkeysG, blabsG,
                                    text_memo, text_embeds, SQ);
    kC_cosin<<<1024, 256, 0, stream>>>(SQ, text_embeds, out);
}

// Round 25
// 35.731 us; speedup vs baseline: 1.0796x; 1.0796x over previous
//
#include <hip/hip_runtime.h>

#define B 16384
#define C 4
#define M 512
#define D 512
#define NSEG 64   // B/256 candidate segments
#define QSCALE 16777216.0f   // 2^24 fixed-point scale for deterministic atomics
#define BCAP_G 2048          // global boundary list capacity
#define BCAP_S 1024          // LDS copy capacity in kB (expected nb ~ 44)

// normalize -0.0 -> +0.0 so positive-float bit ordering is valid
__device__ inline unsigned posbits(float e)
{
    unsigned b = __float_as_uint(e);
    return (b == 0x80000000u) ? 0u : b;
}
// monotone (non-strict) 8-bit bin of the entropy; ent in [0, ln4]
__device__ inline int binOfBits(unsigned bits)
{
    float e = __uint_as_float(bits);
    float s = fminf(fmaxf(e * 12000000.0f, 0.0f), 16777215.0f);
    return (int)((unsigned)s >> 16);
}

// ---------------- K1: stats + candList + per-segment ushort histogram ------
__global__ __launch_bounds__(256) void k1_stats(
    const float* __restrict__ logits,
    const float* __restrict__ ent_memo,
    float* __restrict__ out,
    int* __restrict__ blockCnt,
    uint2* __restrict__ candList,
    unsigned long long* __restrict__ SQ,
    unsigned* __restrict__ hist_part,   // [NSEG][512] packed 2x ushort
    int* __restrict__ bnumG)
{
    __shared__ int wscan[4];
    __shared__ int lh[1024];            // [lab*256+bin]
    const int tid = threadIdx.x, blk = blockIdx.x;
    const int gid = blk * 256 + tid;
    const int lane = tid & 63, wv = tid >> 6;

    for (int i = tid; i < 1024; i += 256) lh[i] = 0;

    float4 l = *reinterpret_cast<const float4*>(logits + (size_t)gid * 4);
    float m = l.x; int idx = 0;
    if (l.y > m) { m = l.y; idx = 1; }
    if (l.z > m) { m = l.z; idx = 2; }
    if (l.w > m) { m = l.w; idx = 3; }
    float e0 = expf(l.x - m), e1 = expf(l.y - m), e2 = expf(l.z - m), e3 = expf(l.w - m);
    float s = e0 + e1 + e2 + e3;
    float inv = 1.0f / s;
    float p0 = e0 * inv, p1 = e1 * inv, p2 = e2 * inv, p3 = e3 * inv;
    float lse = logf(s);
    float ent = -(p0 * (l.x - m - lse) + p1 * (l.y - m - lse)
                + p2 * (l.z - m - lse) + p3 * (l.w - m - lse));
    float4 pr = { p0, p1, p2, p3 };
    *reinterpret_cast<float4*>(out + (size_t)B * 4 + (size_t)gid * 4) = pr;
    out[(size_t)B * 8 + gid] = ent;

    if (gid < C * M) SQ[gid] = 0ULL;
    if (gid == 0) *bnumG = 0;

    float amax = ent_memo[(idx << 9) + M - 1];
    bool flag = ent < amax;
    unsigned bits = posbits(ent);
    __syncthreads();                     // lh zeroed

    if (flag) atomicAdd(&lh[(idx << 8) | binOfBits(bits)], 1);
    if (blk < 8) {                       // memo rows ride on blocks 0..7
        unsigned mb = posbits(ent_memo[gid]);
        atomicAdd(&lh[((gid >> 9) << 8) | binOfBits(mb)], 1);
    }

    // block-level compaction (order = b ascending within segment)
    unsigned long long mask = __ballot(flag);
    int prefix = __popcll(mask & ((1ull << lane) - 1ull));
    if (lane == 0) wscan[wv] = __popcll(mask);
    __syncthreads();                     // wscan ready + lh adds done
    int base = 0;
    for (int w = 0; w < wv; w++) base += wscan[w];
    if (flag)
        candList[blk * 256 + base + prefix] =
            make_uint2(bits, ((unsigned)idx << 14) | (unsigned)gid);
    if (tid == 0)
        blockCnt[blk] = wscan[0] + wscan[1] + wscan[2] + wscan[3];

    // packed write: entry pair (2i, 2i+1) -> one uint (counts <= 256, fits)
    for (int i = tid; i < 512; i += 256)
        hist_part[blk * 512 + i] = (unsigned)lh[2 * i] | ((unsigned)lh[2 * i + 1] << 16);
}

// ---------------- KT: hist reduce + scan + boundary extraction (72 blocks) -
__global__ __launch_bounds__(256) void kT_extract(
    const int* __restrict__ blockCnt,
    const uint2* __restrict__ candList,
    const float* __restrict__ ent_memo,
    const unsigned* __restrict__ hist_part,
    int* __restrict__ mremG,
    int* __restrict__ bnumG,
    unsigned long long* __restrict__ bkeysG,
    int* __restrict__ blabsG)
{
    __shared__ int hist_s[1024];
    __shared__ int betaS[4], mremS[4];
    const int x = blockIdx.x, tid = threadIdx.x;
    const int lane = tid & 63, sg = tid >> 6;

    // reduce hist_part (packed adds, no carry possible)
    {
        unsigned a0 = 0u, a1 = 0u;
        for (int sb = 0; sb < NSEG; sb += 8) {
            unsigned v0[8], v1[8];
            #pragma unroll
            for (int u = 0; u < 8; u++) {
                v0[u] = hist_part[(sb + u) * 512 + tid];
                v1[u] = hist_part[(sb + u) * 512 + 256 + tid];
            }
            #pragma unroll
            for (int u = 0; u < 8; u++) { a0 += v0[u]; a1 += v1[u]; }
        }
        hist_s[2 * tid]           = (int)(a0 & 0xFFFFu);
        hist_s[2 * tid + 1]       = (int)(a0 >> 16);
        hist_s[512 + 2 * tid]     = (int)(a1 & 0xFFFFu);
        hist_s[512 + 2 * tid + 1] = (int)(a1 >> 16);
    }
    __syncthreads();

    // per-wave scan (wave w = label w), barrier-free within wave
    if (sg < 4) {
        int b0 = hist_s[(sg << 8) | (lane * 4 + 0)];
        int b1 = hist_s[(sg << 8) | (lane * 4 + 1)];
        int b2 = hist_s[(sg << 8) | (lane * 4 + 2)];
        int b3 = hist_s[(sg << 8) | (lane * 4 + 3)];
        int loc = b0 + b1 + b2 + b3;
        int scan = loc;
        #pragma unroll
        for (int off = 1; off < 64; off <<= 1) {
            int n = __shfl_up(scan, off, 64);
            if (lane >= off) scan += n;
        }
        int excl = scan - loc;
        int c0 = excl + b0, c1 = c0 + b1, c2 = c1 + b2, c3 = c2 + b3;
        if (excl < M && c3 >= M) {          // exactly one lane per label
            int beta, mrem;
            if (c0 >= M)      { beta = lane * 4 + 0; mrem = M - excl; }
            else if (c1 >= M) { beta = lane * 4 + 1; mrem = M - c0; }
            else if (c2 >= M) { beta = lane * 4 + 2; mrem = M - c1; }
            else              { beta = lane * 4 + 3; mrem = M - c2; }
            betaS[sg] = beta; mremS[sg] = mrem;
        }
    }
    __syncthreads();
    if (x == 0 && tid < 4) mremG[tid] = mremS[tid];

    if (x < NSEG) {
        uint2 v = candList[x * 256 + tid];
        int lab = (int)((v.y >> 14) & 3);
        if (tid < blockCnt[x] && binOfBits(v.x) == betaS[lab]) {
            int id = atomicAdd(bnumG, 1);
            if (id < BCAP_G) {
                bkeysG[id] = ((unsigned long long)v.x << 15)
                           | (unsigned)(512 + (v.y & 0x3FFF));
                blabsG[id] = lab;
            }
        }
    } else {
        int i = (x - NSEG) * 256 + tid;     // [0, C*M)
        unsigned bits = posbits(ent_memo[i]);
        int lab = i >> 9;
        if (binOfBits(bits) == betaS[lab]) {
            int id = atomicAdd(bnumG, 1);
            if (id < BCAP_G) {
                bkeysG[id] = ((unsigned long long)bits << 15) | (unsigned)(i & (M - 1));
                blabsG[id] = lab;
            }
        }
    }
}

// ---------------- KB: light preamble + compacted gather -> SQ --------------
// blocks 0..511: batch, seg = x>>3, colchunk q = x&7.  512..575: memo groups.
// Batch gather iterates ONLY kept slots (ballot-compacted, slot-ascending =>
// deterministic partial order). Fixed-order fp32 partials -> int64 atomics.
__global__ __launch_bounds__(256) void kB_acc(
    const int* __restrict__ blockCnt,
    const uint2* __restrict__ candList,
    const float* __restrict__ ent_memo,
    const int* __restrict__ mremG,
    const int* __restrict__ bnumG,
    const unsigned long long* __restrict__ bkeysG,
    const int* __restrict__ blabsG,
    const float* __restrict__ text_memo,
    const float* __restrict__ text_embeds,
    unsigned long long* __restrict__ SQ)
{
    __shared__ unsigned long long bkeys[BCAP_S];  // 8 KB
    __shared__ int blabs[BCAP_S];                 // 4 KB
    __shared__ int mremS[4];
    __shared__ unsigned long long TkeyS[4];
    __shared__ int meta[256];
    __shared__ int wscan[4];
    __shared__ int kcS;
    __shared__ float red[4][4][64];               // 4 KB [sg][label][lane]

    const int x = blockIdx.x, tid = threadIdx.x;
    const int col0 = (x & 7) << 6;
    const int lane = tid & 63, sg = tid >> 6;

    // ---- light select preamble (identical & deterministic in every block) -
    int nb = *bnumG; if (nb > BCAP_S) nb = BCAP_S;
    if (tid < 4) { mremS[tid] = mremG[tid]; TkeyS[tid] = ~0ULL; }
    for (int i = tid; i < nb; i += 256) { bkeys[i] = bkeysG[i]; blabs[i] = blabsG[i]; }
    __syncthreads();
    for (int t = tid; t < nb; t += 256) {
        unsigned long long k = bkeys[t]; int l = blabs[t];
        int r = 0;
        for (int j = 0; j < nb; j++)
            if (blabs[j] == l && bkeys[j] < k) r++;
        if (r == mremS[l] - 1) TkeyS[l] = k;      // unique winner (keys unique)
    }
    __syncthreads();                              // TkeyS visible to all waves

    if (x < 512) {
        const int seg = x >> 3;
        const int cnt = blockCnt[seg];
        // ---- ballot-compact kept slots (slot-ascending, deterministic) ----
        {
            uint2 v = candList[(seg << 8) + tid];
            int lab = (int)((v.y >> 14) & 3);
            unsigned long long key = ((unsigned long long)v.x << 15)
                                   | (unsigned)(512 + (v.y & 0x3FFF));
            bool kept = (tid < cnt) && (key <= TkeyS[lab]);
            unsigned long long kmask = __ballot(kept);
            int prefix = __popcll(kmask & ((1ull << lane) - 1ull));
            if (lane == 0) wscan[sg] = __popcll(kmask);
            meta[tid] = 0;                        // zero-pad (kept bit clear)
            __syncthreads();
            int base = 0;
            for (int w = 0; w < sg; w++) base += wscan[w];
            if (kept)
                meta[base + prefix] = (int)((unsigned)lab | 4u | ((v.y & 0x3FFF) << 3));
            if (tid == 0) kcS = wscan[0] + wscan[1] + wscan[2] + wscan[3];
            __syncthreads();
        }
        const int kcp = (kcS + 31) & ~31;         // padded to 32 (pads add 0)
        float a0 = 0.f, a1 = 0.f, a2 = 0.f, a3 = 0.f;
        for (int i0 = 0; i0 < kcp; i0 += 32) {
            int mts[8]; float vvs[8];
            #pragma unroll
            for (int u = 0; u < 8; u++)
                mts[u] = meta[i0 + ((u << 2) | sg)];
            #pragma unroll
            for (int u = 0; u < 8; u++)
                vvs[u] = text_embeds[(size_t)(mts[u] >> 3) * D + col0 + lane];
            #pragma unroll
            for (int u = 0; u < 8; u++) {
                bool kept = (mts[u] & 4) != 0;
                int lb = mts[u] & 3;
                float vv = vvs[u];
                a0 += (kept && lb == 0) ? vv : 0.f;
                a1 += (kept && lb == 1) ? vv : 0.f;
                a2 += (kept && lb == 2) ? vv : 0.f;
                a3 += (kept && lb == 3) ? vv : 0.f;
            }
        }
        red[sg][0][lane] = a0; red[sg][1][lane] = a1;
        red[sg][2][lane] = a2; red[sg][3][lane] = a3;
        __syncthreads();
        {
            int lab = tid >> 6, ln = tid & 63;
            float t = ((red[0][lab][ln] + red[1][lab][ln])
                     + red[2][lab][ln]) + red[3][lab][ln];   // fixed order
            long long q = llrintf(t * QSCALE);
            atomicAdd(&SQ[(lab << 9) + col0 + ln], (unsigned long long)q);
        }
    } else {
        const int g = (x - 512) >> 3;               // rowgroup 0..7
        const int c = g >> 1;                       // label
        const int base = g << 8;                    // first global memo row
        {
            int i = base + tid;
            unsigned bits = posbits(ent_memo[i]);
            unsigned long long key = ((unsigned long long)bits << 15)
                                   | (unsigned)(i & (M - 1));
            meta[tid] = (key <= TkeyS[c]) ? 1 : 0;
        }
        __syncthreads();
        float a = 0.f;
        #pragma unroll
        for (int kb = 0; kb < 8; kb++) {
            float vvs[8];
            #pragma unroll
            for (int u = 0; u < 8; u++)
                vvs[u] = text_memo[(size_t)(base + ((((kb << 3) | u) << 2) | sg)) * D + col0 + lane];
            #pragma unroll
            for (int u = 0; u < 8; u++)
                a += meta[(((kb << 3) | u) << 2) | sg] ? vvs[u] : 0.f;
        }
        red[sg][0][lane] = a;
        __syncthreads();
        if (tid < 64) {
            float t = ((red[0][0][tid] + red[1][0][tid])
                     + red[2][0][tid]) + red[3][0][tid];     // fixed order
            long long q = llrintf(t * QSCALE);
            atomicAdd(&SQ[(c << 9) + col0 + tid], (unsigned long long)q);
        }
    }
}

// ---------------- KC: SQ->VGPR S + GEMV + combines + softmaxes -------------
__global__ __launch_bounds__(256) void kC_cosin(
    const unsigned long long* __restrict__ SQ,
    const float* __restrict__ text_embeds,
    float* __restrict__ out)
{
    const int tid = threadIdx.x;
    const int wave = tid >> 6, lane = tid & 63;
    const float sc = 1.0f / QSCALE;
    float s0[8], s1[8], s2[8], s3[8];
    #pragma unroll
    for (int j = 0; j < 8; j++) {
        s0[j] = (float)(long long)SQ[0 * 512 + lane * 8 + j] * sc;
        s1[j] = (float)(long long)SQ[1 * 512 + lane * 8 + j] * sc;
        s2[j] = (float)(long long)SQ[2 * 512 + lane * 8 + j] * sc;
        s3[j] = (float)(long long)SQ[3 * 512 + lane * 8 + j] * sc;
    }
    for (int r4 = 0; r4 < 4; r4++) {
        int b = blockIdx.x * 16 + wave * 4 + r4;
        const float4* te4 = reinterpret_cast<const float4*>(text_embeds + (size_t)b * D);
        float4 t0 = te4[lane * 2], t1 = te4[lane * 2 + 1];
        float te[8] = { t0.x, t0.y, t0.z, t0.w, t1.x, t1.y, t1.z, t1.w };
        float c0 = 0.f, c1 = 0.f, c2 = 0.f, c3 = 0.f;
        #pragma unroll
        for (int j = 0; j < 8; j++) {
            c0 += te[j] * s0[j];
            c1 += te[j] * s1[j];
            c2 += te[j] * s2[j];
            c3 += te[j] * s3[j];
        }
        for (int off = 32; off; off >>= 1) {
            c0 += __shfl_down(c0, off, 64);
            c1 += __shfl_down(c1, off, 64);
            c2 += __shfl_down(c2, off, 64);
            c3 += __shfl_down(c3, off, 64);
        }
        if (lane == 0) {
            float t0c = c0 + c2, t1c = c1 + c3;   // text_combine
            float v0c = c0 + c1, v1c = c2 + c3;   // vision_combine
            float tm = fmaxf(t0c, t1c);
            float te0 = expf(t0c - tm), te1 = expf(t1c - tm);
            float ts = te0 + te1;
            float mt0 = te0 / ts, mt1 = te1 / ts;
            float vm = fmaxf(v0c, v1c);
            float ve0 = expf(v0c - vm), ve1 = expf(v1c - vm);
            float vs = ve0 + ve1;
            float mv0 = ve0 / vs, mv1 = ve1 / vs;
            float4 o = { mt0 * mv0, mt1 * mv0, mt0 * mv1, mt1 * mv1 };
            *reinterpret_cast<float4*>(out + (size_t)b * 4) = o;
        }
    }
}

// ---------------------------------------------------------------------------
extern "C" void kernel_launch(void* const* d_in, const int* in_sizes, int n_in,
                              void* d_out, int out_size, void* d_ws, size_t ws_size,
                              hipStream_t stream)
{
    (void)in_sizes; (void)n_in; (void)out_size; (void)ws_size;
    const float* logits      = (const float*)d_in[0];
    const float* text_embeds = (const float*)d_in[1];
    const float* ent_memo    = (const float*)d_in[3];
    const float* text_memo   = (const float*)d_in[4];
    float* out = (float*)d_out;
    char* ws = (char*)d_ws;

    // workspace layout (bytes), 256-aligned
    int*   blockCnt = (int*)(ws + 0);                        // 256 B
    uint2* candList = (uint2*)(ws + 256);                    // 128 KB -> 131328
    unsigned long long* SQ = (unsigned long long*)(ws + 131328); // 16 KB -> 147712
    unsigned* hist_part = (unsigned*)(ws + 147712);          // 128 KB -> 278784
    int* mremG = (int*)(ws + 278784);                        // 64 B
    int* bnumG = (int*)(ws + 279040);                        // 64 B
    unsigned long long* bkeysG = (unsigned long long*)(ws + 279296); // 16 KB -> 295680
    int* blabsG = (int*)(ws + 295680);                       // 8 KB -> 303872

    k1_stats<<<NSEG, 256, 0, stream>>>(logits, ent_memo, out, blockCnt,
                                       candList, SQ, hist_part, bnumG);
    kT_extract<<<NSEG + 8, 256, 0, stream>>>(blockCnt, candList, ent_memo,
                                             hist_part, mremG, bnumG,
                                             bkeysG, blabsG);
    kB_acc<<<576, 256, 0, stream>>>(blockCnt, candList, ent_memo,
                                    mremG, bnumG, bkeysG, blabsG,
                                    text_memo, text_embeds, SQ);
    kC_cosin<<<1024, 256, 0, stream>>>(SQ, text_embeds, out);
}